// Round 17
// baseline (39.014 us; speedup 1.0000x reference)
//
#include <hip/hip_runtime.h>
#include <hip/hip_fp16.h>

#define B_  64
#define L_  512
#define D_  768
#define S_  64
#define N1_ 384
#define N2_ 128

typedef __attribute__((ext_vector_type(8))) _Float16 half8;
typedef __attribute__((ext_vector_type(8))) short short8v;
typedef __attribute__((ext_vector_type(4))) float f32x4;

__device__ __forceinline__ ushort f2h(float x) {
  return __half_as_ushort(__float2half_rn(x));
}

// ---------------------------------------------------------------------------
// Kernel A: weight swizzle to MFMA B-fragment lane order (proven R13/R14).
// blob(ntile,kt)[lane][e] = W[kt*32+(lane>>4)*8+e][ntile*16+(lane&15)].
// ---------------------------------------------------------------------------
__global__ __launch_bounds__(192) void wswz_kernel(
    const float* __restrict__ W1, ushort* __restrict__ w1s,
    const float* __restrict__ W2, ushort* __restrict__ w2s) {
  const int bid = blockIdx.x;
  const int tid = threadIdx.x;
  if (bid < 24) {
    const int n0 = bid * 16;
    #pragma unroll 1
    for (int i = 0; i < 8; ++i) {
      const int slot = i * 192 + tid;          // 0..1535
      const int kt = slot >> 6, l = slot & 63;
      short8v r;
      #pragma unroll
      for (int e = 0; e < 8; ++e) {
        float x = W1[(size_t)(kt * 32 + ((l >> 4) << 3) + e) * N1_ + n0 + (l & 15)];
        r[e] = (short)f2h(x);
      }
      *(short8v*)(w1s + ((size_t)bid * 1536 + slot) * 8) = r;
    }
  } else {
    const int wb = bid - 24;
    const int n0 = wb * 16;
    #pragma unroll 1
    for (int i = 0; i < 4; ++i) {
      const int slot = i * 192 + tid;          // 0..767
      const int kt = slot >> 6, l = slot & 63;
      short8v r;
      #pragma unroll
      for (int e = 0; e < 8; ++e) {
        float x = W2[(size_t)(kt * 32 + ((l >> 4) << 3) + e) * N2_ + n0 + (l & 15)];
        r[e] = (short)f2h(x);
      }
      *(short8v*)(w2s + ((size_t)wb * 768 + slot) * 8) = r;
    }
  }
}

// ---------------------------------------------------------------------------
// Kernel B: fused mean+MLP per EIGHTH-sample (8 segments). 512 blocks x 512
// thr -> 2 blocks/CU co-resident: one block's HBM stream overlaps the other's
// MFMA/L2 phases. MFMA tiles are 16-row; rows 8..15 carry garbage (harmless:
// C rows depend only on matching A rows; all writes guarded to rows < 8).
// ---------------------------------------------------------------------------
__global__ __launch_bounds__(512, 4) void fused_all(
    const float* __restrict__ hidden, const int* __restrict__ seg_ids,
    const ushort* __restrict__ w1s, const float* __restrict__ b1,
    const ushort* __restrict__ w2s, const float* __restrict__ b2,
    const float* __restrict__ W3, const float* __restrict__ b3,
    float* __restrict__ out) {
  __shared__ __align__(16) char lds[39584];
  int*    sids = (int*)lds;                     // 2048 B
  ushort* sM   = (ushort*)(lds + 2048);         // [16][776] (rows 8+ unused)
  ushort* sH   = (ushort*)(lds + 26880);        // [16][392] (rows 8+ unused)
  float*  pl   = (float*)(lds + 39424);         // 16 floats
  int*    wred = (int*)(lds + 39552);           // 4 ints

  const int tid  = threadIdx.x;
  const int wid  = tid >> 6;
  const int lane = tid & 63;
  const int lrow = lane & 15;
  const int lk   = (lane >> 4) * 8;
  const int b    = blockIdx.x >> 3;
  const int q8   = blockIdx.x & 7;
  const int s0   = q8 * 8;                      // 8 segments per block
  const int row0 = b * 64 + s0;

  if (tid < 128)
    ((int4*)sids)[tid] = ((const int4*)(seg_ids + b * L_))[tid];
  if (tid < 16) pl[tid] = 0.0f;
  __syncthreads();

  // ---- bounds per 4-segment group (g=0,1; threads 384..511 idle) ----
  const int g  = tid / 192;
  const int gt = tid - g * 192;
  if (g < 2) {
    const int s0g = s0 + g * 4;
    int pk = 0;
    if (gt < 128) {
      int4 v = ((const int4*)sids)[gt];
      int clo = (v.x < s0g) + (v.y < s0g) + (v.z < s0g) + (v.w < s0g);
      int chi = (v.x < s0g + 4) + (v.y < s0g + 4) +
                (v.z < s0g + 4) + (v.w < s0g + 4);
      pk = clo * 1024 + chi;
    }
    #pragma unroll
    for (int off = 1; off < 64; off <<= 1) pk += __shfl_xor(pk, off);
    if (gt < 128 && (gt & 63) == 0) wred[g * 2 + (gt >> 6)] = pk;
  }
  __syncthreads();

  // ---- stream this group's 4 segments' token span -> sM rows ----
  if (g < 2) {
    const int s0g = s0 + g * 4;
    const int tot = wred[g * 2] + wred[g * 2 + 1];
    const int lo = tot >> 10;
    const int hi = tot & 1023;

    const float4* hp = (const float4*)(hidden + (size_t)b * L_ * D_) + gt;
    const uint2 zz = {0u, 0u};

    int cur = (lo < hi) ? sids[lo] : s0g + 4;
    for (int z = s0g; z < cur; ++z)
      *(uint2*)(sM + (z - s0) * 776 + gt * 4) = zz;

    float4 acc = {0.0f, 0.0f, 0.0f, 0.0f};
    int segstart = lo;
    for (int l = lo; l < hi; l += 8) {
      float4 v[8];
      int sv[8];
      #pragma unroll
      for (int k = 0; k < 8; ++k) {
        v[k]  = hp[(size_t)min(l + k, hi - 1) * (D_ / 4)];
        sv[k] = sids[min(l + k + 1, hi - 1)];
      }
      #pragma unroll
      for (int k = 0; k < 8; ++k) {
        if (l + k < hi) {
          acc.x += v[k].x; acc.y += v[k].y;
          acc.z += v[k].z; acc.w += v[k].w;
          const int nx = l + k + 1;
          if (nx == hi || sv[k] != cur) {
            const float inv = 1.0f / (float)(nx - segstart);
            ushort4 h;
            h.x = f2h(acc.x * inv); h.y = f2h(acc.y * inv);
            h.z = f2h(acc.z * inv); h.w = f2h(acc.w * inv);
            *(ushort4*)(sM + (cur - s0) * 776 + gt * 4) = h;
            const int nxt = (nx == hi) ? s0g + 4 : sv[k];
            for (int z = cur + 1; z < nxt; ++z)
              *(uint2*)(sM + (z - s0) * 776 + gt * 4) = zz;
            acc.x = 0.0f; acc.y = 0.0f; acc.z = 0.0f; acc.w = 0.0f;
            segstart = nx; cur = nxt;
          }
        }
      }
    }
  }
  __syncthreads();

  // ---- phase 1: 24 barrier-free k-tiles; wave owns W1 ntiles 3w..3w+2 ----
  f32x4 acc1[3] = {};
  {
    const ushort* bp = w1s + (size_t)(3 * wid) * 24 * 512 + lane * 8;
    #pragma unroll 4
    for (int kt = 0; kt < 24; ++kt) {
      half8 af = *(const half8*)&sM[lrow * 776 + kt * 32 + lk];
      half8 bf[3];
      #pragma unroll
      for (int j = 0; j < 3; ++j)
        bf[j] = *(const half8*)(bp + ((size_t)j * 24 + kt) * 512);
      #pragma unroll
      for (int j = 0; j < 3; ++j)
        acc1[j] = __builtin_amdgcn_mfma_f32_16x16x32_f16(af, bf[j], acc1[j], 0, 0, 0);
    }
  }
  // h1 -> LDS (rows < 8 only; lane>>4 >= 2 holds garbage rows)
  if (lane < 32) {
    #pragma unroll
    for (int j = 0; j < 3; ++j) {
      const int n = (3 * wid + j) * 16 + lrow;
      const float bj = b1[n];
      #pragma unroll
      for (int r = 0; r < 4; ++r) {
        const int m = (lane >> 4) * 4 + r;    // 0..7
        sH[m * 392 + n] = f2h(fmaxf(acc1[j][r] + bj, 0.0f));
      }
    }
  }
  __syncthreads();

  // ---- phase 2: 12 k-tiles; wave owns W2 ntile = wid ----
  f32x4 a2 = {};
  {
    const ushort* bp = w2s + (size_t)wid * 12 * 512 + lane * 8;
    #pragma unroll 4
    for (int kt = 0; kt < 12; ++kt) {
      half8 af = *(const half8*)&sH[lrow * 392 + kt * 32 + lk];
      half8 bf = *(const half8*)(bp + (size_t)kt * 512);
      a2 = __builtin_amdgcn_mfma_f32_16x16x32_f16(af, bf, a2, 0, 0, 0);
    }
  }

  // ---- epilogue: h2 = relu(a2 + b2); logits = h2 @ W3 + b3 (rows < 8) ----
  const int col = wid * 16 + lrow;
  const float w30 = W3[col * 2 + 0];
  const float w31 = W3[col * 2 + 1];
  const float b2v = b2[col];
  #pragma unroll
  for (int r = 0; r < 4; ++r) {
    float v = fmaxf(a2[r] + b2v, 0.0f);
    float p0 = v * w30;
    float p1 = v * w31;
    p0 += __shfl_xor(p0, 1); p1 += __shfl_xor(p1, 1);
    p0 += __shfl_xor(p0, 2); p1 += __shfl_xor(p1, 2);
    p0 += __shfl_xor(p0, 4); p1 += __shfl_xor(p1, 4);
    p0 += __shfl_xor(p0, 8); p1 += __shfl_xor(p1, 8);
    if (lrow == 0 && lane < 32) {
      const int row = (lane >> 4) * 4 + r;   // 0..7
      atomicAdd(&pl[row * 2 + 0], p0);
      atomicAdd(&pl[row * 2 + 1], p1);
    }
  }
  __syncthreads();
  if (tid < 16) {
    const int row = tid >> 1, c = tid & 1;
    out[(size_t)(row0 + row) * 2 + c] = pl[tid] + b3[c];
  }
}

// ---------------------------------------------------------------------------
extern "C" void kernel_launch(void* const* d_in, const int* in_sizes, int n_in,
                              void* d_out, int out_size, void* d_ws, size_t ws_size,
                              hipStream_t stream) {
  const float* hidden  = (const float*)d_in[0];
  const int*   seg_ids = (const int*)d_in[1];
  const float* W1 = (const float*)d_in[2];
  const float* b1 = (const float*)d_in[3];
  const float* W2 = (const float*)d_in[4];
  const float* b2 = (const float*)d_in[5];
  const float* W3 = (const float*)d_in[6];
  const float* b3 = (const float*)d_in[7];
  float* out = (float*)d_out;

  char* p = (char*)d_ws;
  ushort* w1s = (ushort*)p;  p += (size_t)N1_ * D_ * 2;     // 0.59 MB swizzled
  ushort* w2s = (ushort*)p;  p += (size_t)N2_ * N1_ * 2;    // 98 KB swizzled

  wswz_kernel<<<32, 192, 0, stream>>>(W1, w1s, W2, w2s);
  fused_all<<<B_ * 8, 512, 0, stream>>>(
      hidden, seg_ids, w1s, b1, w2s, b2, W3, b3, out);
}

// Round 18
// 38.758 us; speedup vs baseline: 1.0066x; 1.0066x over previous
//
#include <hip/hip_runtime.h>
#include <hip/hip_fp16.h>

#define B_  64
#define L_  512
#define D_  768
#define S_  64
#define N1_ 384
#define N2_ 128

typedef __attribute__((ext_vector_type(8))) _Float16 half8;
typedef __attribute__((ext_vector_type(8))) short short8v;
typedef __attribute__((ext_vector_type(4))) float f32x4;

__device__ __forceinline__ ushort f2h(float x) {
  return __half_as_ushort(__float2half_rn(x));
}

// ---------------------------------------------------------------------------
// Kernel A: weight swizzle to MFMA B-fragment lane order (proven R13/R14).
// blob(ntile,kt)[lane][e] = W[kt*32+(lane>>4)*8+e][ntile*16+(lane&15)].
// ---------------------------------------------------------------------------
__global__ __launch_bounds__(192) void wswz_kernel(
    const float* __restrict__ W1, ushort* __restrict__ w1s,
    const float* __restrict__ W2, ushort* __restrict__ w2s) {
  const int bid = blockIdx.x;
  const int tid = threadIdx.x;
  if (bid < 24) {
    const int n0 = bid * 16;
    #pragma unroll 1
    for (int i = 0; i < 8; ++i) {
      const int slot = i * 192 + tid;          // 0..1535
      const int kt = slot >> 6, l = slot & 63;
      short8v r;
      #pragma unroll
      for (int e = 0; e < 8; ++e) {
        float x = W1[(size_t)(kt * 32 + ((l >> 4) << 3) + e) * N1_ + n0 + (l & 15)];
        r[e] = (short)f2h(x);
      }
      *(short8v*)(w1s + ((size_t)bid * 1536 + slot) * 8) = r;
    }
  } else {
    const int wb = bid - 24;
    const int n0 = wb * 16;
    #pragma unroll 1
    for (int i = 0; i < 4; ++i) {
      const int slot = i * 192 + tid;          // 0..767
      const int kt = slot >> 6, l = slot & 63;
      short8v r;
      #pragma unroll
      for (int e = 0; e < 8; ++e) {
        float x = W2[(size_t)(kt * 32 + ((l >> 4) << 3) + e) * N2_ + n0 + (l & 15)];
        r[e] = (short)f2h(x);
      }
      *(short8v*)(w2s + ((size_t)wb * 768 + slot) * 8) = r;
    }
  }
}

// ---------------------------------------------------------------------------
// Kernel B: fused mean+MLP per quarter-sample (16 segments) — R16 geometry —
// but 256 THREADS (4 waves) so 2-4 blocks/CU co-reside: one block's HBM
// stream overlaps neighbors' MFMA/L2 phases. Weight traffic unchanged vs R16
// (256 blocks), full 16-row MFMA tiles (no garbage rows).
//  stream: 192 threads, R9-proven masked-batch boundary-flush -> sM in LDS.
//  phase1: wave owns 6 W1 ntiles (24/4), 24 barrier-free k-tiles.
//  phase2: wave owns 2 W2 ntiles; W3 shfl-reduce epilogue -> out.
// ---------------------------------------------------------------------------
__global__ __launch_bounds__(256, 4) void fused_all(
    const float* __restrict__ hidden, const int* __restrict__ seg_ids,
    const ushort* __restrict__ w1s, const float* __restrict__ b1,
    const ushort* __restrict__ w2s, const float* __restrict__ b2,
    const float* __restrict__ W3, const float* __restrict__ b3,
    float* __restrict__ out) {
  __shared__ __align__(16) char lds[39584];
  int*    sids = (int*)lds;                     // 2048 B
  ushort* sM   = (ushort*)(lds + 2048);         // [16][776] = 24832 B
  ushort* sH   = (ushort*)(lds + 26880);        // [16][392] = 12544 B
  float*  pl   = (float*)(lds + 39424);         // 32 floats
  int*    wred = (int*)(lds + 39552);           // 2 ints

  const int tid  = threadIdx.x;
  const int wid  = tid >> 6;
  const int lane = tid & 63;
  const int lrow = lane & 15;
  const int lk   = (lane >> 4) * 8;
  const int b    = blockIdx.x >> 2;
  const int qs   = blockIdx.x & 3;
  const int s0   = qs * 16;
  const int row0 = b * 64 + s0;

  if (tid < 128)
    ((int4*)sids)[tid] = ((const int4*)(seg_ids + b * L_))[tid];
  if (tid < 32) pl[tid] = 0.0f;
  __syncthreads();

  // ---- bounds for [s0, s0+16): threads 0..127 scan, shfl-reduce ----
  {
    int pk = 0;
    if (tid < 128) {
      int4 v = ((const int4*)sids)[tid];
      int clo = (v.x < s0) + (v.y < s0) + (v.z < s0) + (v.w < s0);
      int chi = (v.x < s0 + 16) + (v.y < s0 + 16) +
                (v.z < s0 + 16) + (v.w < s0 + 16);
      pk = clo * 1024 + chi;
    }
    #pragma unroll
    for (int off = 1; off < 64; off <<= 1) pk += __shfl_xor(pk, off);
    if (tid < 128 && (lane == 0)) wred[wid] = pk;
  }
  __syncthreads();

  // ---- stream token span -> means in sM (192 threads own 4 d-cols each) ----
  if (tid < 192) {
    const int gt = tid;
    const int tot = wred[0] + wred[1];
    const int lo = tot >> 10;
    const int hi = tot & 1023;

    const float4* hp = (const float4*)(hidden + (size_t)b * L_ * D_) + gt;
    const uint2 zz = {0u, 0u};

    int cur = (lo < hi) ? sids[lo] : s0 + 16;
    for (int z = s0; z < cur; ++z)
      *(uint2*)(sM + (z - s0) * 776 + gt * 4) = zz;

    float4 acc = {0.0f, 0.0f, 0.0f, 0.0f};
    int segstart = lo;
    for (int l = lo; l < hi; l += 8) {
      float4 v[8];
      int sv[8];
      #pragma unroll
      for (int k = 0; k < 8; ++k) {
        v[k]  = hp[(size_t)min(l + k, hi - 1) * (D_ / 4)];
        sv[k] = sids[min(l + k + 1, hi - 1)];
      }
      #pragma unroll
      for (int k = 0; k < 8; ++k) {
        if (l + k < hi) {
          acc.x += v[k].x; acc.y += v[k].y;
          acc.z += v[k].z; acc.w += v[k].w;
          const int nx = l + k + 1;
          if (nx == hi || sv[k] != cur) {
            const float inv = 1.0f / (float)(nx - segstart);
            ushort4 h;
            h.x = f2h(acc.x * inv); h.y = f2h(acc.y * inv);
            h.z = f2h(acc.z * inv); h.w = f2h(acc.w * inv);
            *(ushort4*)(sM + (cur - s0) * 776 + gt * 4) = h;
            const int nxt = (nx == hi) ? s0 + 16 : sv[k];
            for (int z = cur + 1; z < nxt; ++z)
              *(uint2*)(sM + (z - s0) * 776 + gt * 4) = zz;
            acc.x = 0.0f; acc.y = 0.0f; acc.z = 0.0f; acc.w = 0.0f;
            segstart = nx; cur = nxt;
          }
        }
      }
    }
  }
  __syncthreads();

  // ---- phase 1: 24 barrier-free k-tiles; wave owns W1 ntiles 6w..6w+5 ----
  f32x4 acc1[6] = {};
  {
    const ushort* bp = w1s + (size_t)(6 * wid) * 24 * 512 + lane * 8;
    #pragma unroll 2
    for (int kt = 0; kt < 24; ++kt) {
      half8 af = *(const half8*)&sM[lrow * 776 + kt * 32 + lk];
      half8 bf[6];
      #pragma unroll
      for (int j = 0; j < 6; ++j)
        bf[j] = *(const half8*)(bp + ((size_t)j * 24 + kt) * 512);
      #pragma unroll
      for (int j = 0; j < 6; ++j)
        acc1[j] = __builtin_amdgcn_mfma_f32_16x16x32_f16(af, bf[j], acc1[j], 0, 0, 0);
    }
  }
  #pragma unroll
  for (int j = 0; j < 6; ++j) {
    const int n = (6 * wid + j) * 16 + lrow;
    const float bj = b1[n];
    #pragma unroll
    for (int r = 0; r < 4; ++r) {
      const int m = (lane >> 4) * 4 + r;      // 0..15
      sH[m * 392 + n] = f2h(fmaxf(acc1[j][r] + bj, 0.0f));
    }
  }
  __syncthreads();

  // ---- phase 2: 12 k-tiles; wave owns W2 ntiles 2w, 2w+1 ----
  f32x4 a2[2] = {};
  {
    const ushort* bp = w2s + (size_t)(2 * wid) * 12 * 512 + lane * 8;
    #pragma unroll 2
    for (int kt = 0; kt < 12; ++kt) {
      half8 af = *(const half8*)&sH[lrow * 392 + kt * 32 + lk];
      half8 bf[2];
      bf[0] = *(const half8*)(bp + (size_t)kt * 512);
      bf[1] = *(const half8*)(bp + (size_t)(12 + kt) * 512);
      a2[0] = __builtin_amdgcn_mfma_f32_16x16x32_f16(af, bf[0], a2[0], 0, 0, 0);
      a2[1] = __builtin_amdgcn_mfma_f32_16x16x32_f16(af, bf[1], a2[1], 0, 0, 0);
    }
  }

  // ---- epilogue: h2 = relu(a2 + b2); logits = h2 @ W3 + b3 ----
  #pragma unroll
  for (int j = 0; j < 2; ++j) {
    const int col = (2 * wid + j) * 16 + lrow;
    const float w30 = W3[col * 2 + 0];
    const float w31 = W3[col * 2 + 1];
    const float b2v = b2[col];
    #pragma unroll
    for (int r = 0; r < 4; ++r) {
      float v = fmaxf(a2[j][r] + b2v, 0.0f);
      float p0 = v * w30;
      float p1 = v * w31;
      p0 += __shfl_xor(p0, 1); p1 += __shfl_xor(p1, 1);
      p0 += __shfl_xor(p0, 2); p1 += __shfl_xor(p1, 2);
      p0 += __shfl_xor(p0, 4); p1 += __shfl_xor(p1, 4);
      p0 += __shfl_xor(p0, 8); p1 += __shfl_xor(p1, 8);
      if (lrow == 0) {
        const int row = (lane >> 4) * 4 + r;  // 0..15
        atomicAdd(&pl[row * 2 + 0], p0);
        atomicAdd(&pl[row * 2 + 1], p1);
      }
    }
  }
  __syncthreads();
  if (tid < 32) {
    const int row = tid >> 1, c = tid & 1;
    out[(size_t)(row0 + row) * 2 + c] = pl[tid] + b3[c];
  }
}

// ---------------------------------------------------------------------------
extern "C" void kernel_launch(void* const* d_in, const int* in_sizes, int n_in,
                              void* d_out, int out_size, void* d_ws, size_t ws_size,
                              hipStream_t stream) {
  const float* hidden  = (const float*)d_in[0];
  const int*   seg_ids = (const int*)d_in[1];
  const float* W1 = (const float*)d_in[2];
  const float* b1 = (const float*)d_in[3];
  const float* W2 = (const float*)d_in[4];
  const float* b2 = (const float*)d_in[5];
  const float* W3 = (const float*)d_in[6];
  const float* b3 = (const float*)d_in[7];
  float* out = (float*)d_out;

  char* p = (char*)d_ws;
  ushort* w1s = (ushort*)p;  p += (size_t)N1_ * D_ * 2;     // 0.59 MB swizzled
  ushort* w2s = (ushort*)p;  p += (size_t)N2_ * N1_ * 2;    // 98 KB swizzled

  wswz_kernel<<<32, 192, 0, stream>>>(W1, w1s, W2, w2s);
  fused_all<<<B_ * 4, 256, 0, stream>>>(
      hidden, seg_ids, w1s, b1, w2s, b2, W3, b3, out);
}

// Round 19
// 35.248 us; speedup vs baseline: 1.1068x; 1.0996x over previous
//
#include <hip/hip_runtime.h>
#include <hip/hip_fp16.h>

#define B_  64
#define L_  512
#define D_  768
#define S_  64
#define N1_ 384
#define N2_ 128

typedef __attribute__((ext_vector_type(8))) _Float16 half8;
typedef __attribute__((ext_vector_type(8))) short short8v;
typedef __attribute__((ext_vector_type(4))) float f32x4;

__device__ __forceinline__ ushort f2h(float x) {
  return __half_as_ushort(__float2half_rn(x));
}

// ---------------------------------------------------------------------------
// Kernel A: weight swizzle to MFMA B-fragment lane order (proven R13/R14).
// ---------------------------------------------------------------------------
__global__ __launch_bounds__(192) void wswz_kernel(
    const float* __restrict__ W1, ushort* __restrict__ w1s,
    const float* __restrict__ W2, ushort* __restrict__ w2s) {
  const int bid = blockIdx.x;
  const int tid = threadIdx.x;
  if (bid < 24) {
    const int n0 = bid * 16;
    #pragma unroll 1
    for (int i = 0; i < 8; ++i) {
      const int slot = i * 192 + tid;          // 0..1535
      const int kt = slot >> 6, l = slot & 63;
      short8v r;
      #pragma unroll
      for (int e = 0; e < 8; ++e) {
        float x = W1[(size_t)(kt * 32 + ((l >> 4) << 3) + e) * N1_ + n0 + (l & 15)];
        r[e] = (short)f2h(x);
      }
      *(short8v*)(w1s + ((size_t)bid * 1536 + slot) * 8) = r;
    }
  } else {
    const int wb = bid - 24;
    const int n0 = wb * 16;
    #pragma unroll 1
    for (int i = 0; i < 4; ++i) {
      const int slot = i * 192 + tid;          // 0..767
      const int kt = slot >> 6, l = slot & 63;
      short8v r;
      #pragma unroll
      for (int e = 0; e < 8; ++e) {
        float x = W2[(size_t)(kt * 32 + ((l >> 4) << 3) + e) * N2_ + n0 + (l & 15)];
        r[e] = (short)f2h(x);
      }
      *(short8v*)(w2s + ((size_t)wb * 768 + slot) * 8) = r;
    }
  }
}

// ---------------------------------------------------------------------------
// Kernel B: R16 geometry (best: 256 blocks x 512 thr, quarter-sample, two
// 192-thread stream groups of 8 segments) + SOFTWARE PIPELINING everywhere:
//  - stream loop: double-buffered 8-row register batches (loads for batch
//    k+1 issue before batch k's consume/flush) -> continuous HBM issue
//  - phase1/phase2: double-buffered B-fragment prefetch across k-tiles
// ---------------------------------------------------------------------------
__global__ __launch_bounds__(512, 1) void fused_all(
    const float* __restrict__ hidden, const int* __restrict__ seg_ids,
    const ushort* __restrict__ w1s, const float* __restrict__ b1,
    const ushort* __restrict__ w2s, const float* __restrict__ b2,
    const float* __restrict__ W3, const float* __restrict__ b3,
    float* __restrict__ out) {
  __shared__ __align__(16) char lds[39584];
  int*    sids = (int*)lds;                     // 2048 B
  ushort* sM   = (ushort*)(lds + 2048);         // [16][776] = 24832 B
  ushort* sH   = (ushort*)(lds + 26880);        // [16][392] = 12544 B
  float*  pl   = (float*)(lds + 39424);         // 32 floats
  int*    wred = (int*)(lds + 39552);           // 4 ints

  const int tid  = threadIdx.x;
  const int wid  = tid >> 6;
  const int lane = tid & 63;
  const int lrow = lane & 15;
  const int lk   = (lane >> 4) * 8;
  const int b    = blockIdx.x >> 2;
  const int qs   = blockIdx.x & 3;
  const int s0   = qs * 16;
  const int row0 = b * 64 + s0;

  if (tid < 128)
    ((int4*)sids)[tid] = ((const int4*)(seg_ids + b * L_))[tid];
  if (tid < 32) pl[tid] = 0.0f;
  __syncthreads();

  // ---- bounds per 8-segment group (g=0,1; threads 384..511 idle) ----
  const int g  = tid / 192;
  const int gt = tid - g * 192;
  if (g < 2) {
    const int s0g = s0 + g * 8;
    int pk = 0;
    if (gt < 128) {
      int4 v = ((const int4*)sids)[gt];
      int clo = (v.x < s0g) + (v.y < s0g) + (v.z < s0g) + (v.w < s0g);
      int chi = (v.x < s0g + 8) + (v.y < s0g + 8) +
                (v.z < s0g + 8) + (v.w < s0g + 8);
      pk = clo * 1024 + chi;
    }
    #pragma unroll
    for (int off = 1; off < 64; off <<= 1) pk += __shfl_xor(pk, off);
    if (gt < 128 && (gt & 63) == 0) wred[g * 2 + (gt >> 6)] = pk;
  }
  __syncthreads();

  // ---- stream this group's 8 segments, double-buffered batches ----
  if (g < 2) {
    const int s0g = s0 + g * 8;
    const int tot = wred[g * 2] + wred[g * 2 + 1];
    const int lo = tot >> 10;
    const int hi = tot & 1023;
    const int stride = D_ / 4;

    const float4* hp = (const float4*)(hidden + (size_t)b * L_ * D_) + gt;
    const uint2 zz = {0u, 0u};

    int cur = (lo < hi) ? sids[lo] : s0g + 8;
    for (int z = s0g; z < cur; ++z)
      *(uint2*)(sM + (z - s0) * 776 + gt * 4) = zz;

    float4 acc = {0.0f, 0.0f, 0.0f, 0.0f};
    int segstart = lo;

#define LOADB(V, SV, LL)                                                   \
    _Pragma("unroll")                                                      \
    for (int k = 0; k < 8; ++k) {                                          \
      V[k]  = hp[(size_t)min((LL) + k, hi - 1) * stride];                  \
      SV[k] = sids[min((LL) + k + 1, hi - 1)];                             \
    }

#define CONSB(V, SV, LL)                                                   \
    _Pragma("unroll")                                                      \
    for (int k = 0; k < 8; ++k) {                                          \
      if ((LL) + k < hi) {                                                 \
        acc.x += V[k].x; acc.y += V[k].y;                                  \
        acc.z += V[k].z; acc.w += V[k].w;                                  \
        const int nx = (LL) + k + 1;                                       \
        if (nx == hi || SV[k] != cur) {                                    \
          const float inv = 1.0f / (float)(nx - segstart);                 \
          ushort4 h;                                                       \
          h.x = f2h(acc.x * inv); h.y = f2h(acc.y * inv);                  \
          h.z = f2h(acc.z * inv); h.w = f2h(acc.w * inv);                  \
          *(ushort4*)(sM + (cur - s0) * 776 + gt * 4) = h;                 \
          const int nxt = (nx == hi) ? s0g + 8 : SV[k];                    \
          for (int z = cur + 1; z < nxt; ++z)                              \
            *(uint2*)(sM + (z - s0) * 776 + gt * 4) = zz;                  \
          acc.x = 0.0f; acc.y = 0.0f; acc.z = 0.0f; acc.w = 0.0f;          \
          segstart = nx; cur = nxt;                                        \
        }                                                                  \
      }                                                                    \
    }

    if (lo < hi) {
      float4 va[8]; int sva[8];
      LOADB(va, sva, lo);
      #pragma unroll 1
      for (int l = lo; l < hi; l += 16) {
        float4 vb[8]; int svb[8];
        const bool hasB = (l + 8 < hi);
        if (hasB) LOADB(vb, svb, l + 8);     // issue next batch BEFORE consume
        CONSB(va, sva, l);
        if (hasB) {
          if (l + 16 < hi) LOADB(va, sva, l + 16);
          CONSB(vb, svb, l + 8);
        }
      }
    }
#undef LOADB
#undef CONSB
  }
  __syncthreads();

  // ---- phase 1: 24 k-tiles, bf double-buffered; wave owns ntiles 3w.. ----
  f32x4 acc1[3] = {};
  {
    const ushort* bp = w1s + (size_t)(3 * wid) * 24 * 512 + lane * 8;
    half8 bfA[3], bfB[3];
    #pragma unroll
    for (int j = 0; j < 3; ++j)
      bfA[j] = *(const half8*)(bp + (size_t)(j * 24) * 512);
    #pragma unroll 1
    for (int kt = 0; kt < 24; kt += 2) {
      #pragma unroll
      for (int j = 0; j < 3; ++j)
        bfB[j] = *(const half8*)(bp + ((size_t)j * 24 + kt + 1) * 512);
      half8 af = *(const half8*)&sM[lrow * 776 + kt * 32 + lk];
      #pragma unroll
      for (int j = 0; j < 3; ++j)
        acc1[j] = __builtin_amdgcn_mfma_f32_16x16x32_f16(af, bfA[j], acc1[j], 0, 0, 0);
      if (kt + 2 < 24) {
        #pragma unroll
        for (int j = 0; j < 3; ++j)
          bfA[j] = *(const half8*)(bp + ((size_t)j * 24 + kt + 2) * 512);
      }
      af = *(const half8*)&sM[lrow * 776 + (kt + 1) * 32 + lk];
      #pragma unroll
      for (int j = 0; j < 3; ++j)
        acc1[j] = __builtin_amdgcn_mfma_f32_16x16x32_f16(af, bfB[j], acc1[j], 0, 0, 0);
    }
  }
  #pragma unroll
  for (int j = 0; j < 3; ++j) {
    const int n = (3 * wid + j) * 16 + lrow;
    const float bj = b1[n];
    #pragma unroll
    for (int r = 0; r < 4; ++r) {
      const int m = (lane >> 4) * 4 + r;
      sH[m * 392 + n] = f2h(fmaxf(acc1[j][r] + bj, 0.0f));
    }
  }
  __syncthreads();

  // ---- phase 2: 12 k-tiles, bf double-buffered; wave owns ntile wid ----
  f32x4 a2 = {};
  {
    const ushort* bp = w2s + (size_t)wid * 12 * 512 + lane * 8;
    half8 bA = *(const half8*)(bp);
    #pragma unroll 1
    for (int kt = 0; kt < 12; kt += 2) {
      half8 bB = *(const half8*)(bp + (size_t)(kt + 1) * 512);
      half8 af = *(const half8*)&sH[lrow * 392 + kt * 32 + lk];
      a2 = __builtin_amdgcn_mfma_f32_16x16x32_f16(af, bA, a2, 0, 0, 0);
      if (kt + 2 < 12) bA = *(const half8*)(bp + (size_t)(kt + 2) * 512);
      af = *(const half8*)&sH[lrow * 392 + (kt + 1) * 32 + lk];
      a2 = __builtin_amdgcn_mfma_f32_16x16x32_f16(af, bB, a2, 0, 0, 0);
    }
  }

  // ---- epilogue: h2 = relu(a2 + b2); logits = h2 @ W3 + b3 ----
  const int col = wid * 16 + lrow;
  const float w30 = W3[col * 2 + 0];
  const float w31 = W3[col * 2 + 1];
  const float b2v = b2[col];
  #pragma unroll
  for (int r = 0; r < 4; ++r) {
    float v = fmaxf(a2[r] + b2v, 0.0f);
    float p0 = v * w30;
    float p1 = v * w31;
    p0 += __shfl_xor(p0, 1); p1 += __shfl_xor(p1, 1);
    p0 += __shfl_xor(p0, 2); p1 += __shfl_xor(p1, 2);
    p0 += __shfl_xor(p0, 4); p1 += __shfl_xor(p1, 4);
    p0 += __shfl_xor(p0, 8); p1 += __shfl_xor(p1, 8);
    if (lrow == 0) {
      const int row = (lane >> 4) * 4 + r;   // 0..15
      atomicAdd(&pl[row * 2 + 0], p0);
      atomicAdd(&pl[row * 2 + 1], p1);
    }
  }
  __syncthreads();
  if (tid < 32) {
    const int row = tid >> 1, c = tid & 1;
    out[(size_t)(row0 + row) * 2 + c] = pl[tid] + b3[c];
  }
}

// ---------------------------------------------------------------------------
extern "C" void kernel_launch(void* const* d_in, const int* in_sizes, int n_in,
                              void* d_out, int out_size, void* d_ws, size_t ws_size,
                              hipStream_t stream) {
  const float* hidden  = (const float*)d_in[0];
  const int*   seg_ids = (const int*)d_in[1];
  const float* W1 = (const float*)d_in[2];
  const float* b1 = (const float*)d_in[3];
  const float* W2 = (const float*)d_in[4];
  const float* b2 = (const float*)d_in[5];
  const float* W3 = (const float*)d_in[6];
  const float* b3 = (const float*)d_in[7];
  float* out = (float*)d_out;

  char* p = (char*)d_ws;
  ushort* w1s = (ushort*)p;  p += (size_t)N1_ * D_ * 2;     // 0.59 MB swizzled
  ushort* w2s = (ushort*)p;  p += (size_t)N2_ * N1_ * 2;    // 98 KB swizzled

  wswz_kernel<<<32, 192, 0, stream>>>(W1, w1s, W2, w2s);
  fused_all<<<B_ * 4, 512, 0, stream>>>(
      hidden, seg_ids, w1s, b1, w2s, b2, W3, b3, out);
}